// Round 1
// baseline (647.988 us; speedup 1.0000x reference)
//
#include <hip/hip_runtime.h>
#include <hip/hip_bf16.h>
#include <math.h>

#define BATCH 8192
#define IMG 784  // 28*28

// ---------------------------------------------------------------------------
// K1: encoder — fused e_input construction + conv0(11->3) + conv1(3->1)
// one block per image, 256 threads
// ---------------------------------------------------------------------------
__global__ __launch_bounds__(256) void encoder_kernel(
    const float* __restrict__ x, const int* __restrict__ cls,
    const float* __restrict__ w0,   // [3,11,3,3]
    const float* __restrict__ w1,   // [1,3,3,3]
    float* __restrict__ h_out)      // [B,784]
{
    __shared__ float e_pad[11][30][30];  // zero-padded e_input
    __shared__ float h_pad[3][30][30];   // zero-padded conv0 output

    const int b = blockIdx.x;
    const int tid = threadIdx.x;
    const int myc = cls[b];

    // zero pads
    float* ep = &e_pad[0][0][0];
    for (int i = tid; i < 11 * 900; i += 256) ep[i] = 0.f;
    float* hp = &h_pad[0][0][0];
    for (int i = tid; i < 3 * 900; i += 256) hp[i] = 0.f;
    __syncthreads();

    // fill e_input interior: flat f = ch*784 + r*28 + c ; p = f/11, k = f%11
    // value = (k==0) ? x[b,p] : onehot[k-1]
    for (int idx = tid; idx < 11 * 784; idx += 256) {
        int ch  = idx / 784;
        int rem = idx - ch * 784;
        int p   = idx / 11;
        int k   = idx - p * 11;
        float v = (k == 0) ? x[(size_t)b * IMG + p]
                           : ((k - 1 == myc) ? 1.f : 0.f);
        e_pad[ch][rem / 28 + 1][rem % 28 + 1] = v;
    }
    __syncthreads();

    // conv0: 3 out channels, weights wave-uniform -> s_loads
    for (int pix = tid; pix < 784; pix += 256) {
        int r = pix / 28, c = pix % 28;
        float a0 = 0.f, a1 = 0.f, a2 = 0.f;
#pragma unroll
        for (int i = 0; i < 11; ++i)
#pragma unroll
            for (int dr = 0; dr < 3; ++dr)
#pragma unroll
                for (int dc = 0; dc < 3; ++dc) {
                    float v = e_pad[i][r + dr][c + dc];
                    int wi = (i * 3 + dr) * 3 + dc;
                    a0 += v * w0[wi];
                    a1 += v * w0[99 + wi];
                    a2 += v * w0[198 + wi];
                }
        h_pad[0][r + 1][c + 1] = fmaxf(a0, 0.f);
        h_pad[1][r + 1][c + 1] = fmaxf(a1, 0.f);
        h_pad[2][r + 1][c + 1] = fmaxf(a2, 0.f);
    }
    __syncthreads();

    // conv1: 3->1 + relu, write h
    for (int pix = tid; pix < 784; pix += 256) {
        int r = pix / 28, c = pix % 28;
        float a = 0.f;
#pragma unroll
        for (int i = 0; i < 3; ++i)
#pragma unroll
            for (int dr = 0; dr < 3; ++dr)
#pragma unroll
                for (int dc = 0; dc < 3; ++dc)
                    a += h_pad[i][r + dr][c + dc] * w1[(i * 3 + dr) * 3 + dc];
        h_out[(size_t)b * IMG + pix] = fmaxf(a, 0.f);
    }
}

// ---------------------------------------------------------------------------
// K2: fc1 GEMM  h1[8192,400] = relu(h[8192,784] @ w^T + b)
// BM=64 BN=64 BK=16, 256 threads, 4x4 per thread
// ---------------------------------------------------------------------------
__global__ __launch_bounds__(256) void fc1_gemm(
    const float* __restrict__ h,     // [8192,784]
    const float* __restrict__ w,     // [400,784]
    const float* __restrict__ bias,  // [400]
    float* __restrict__ h1)          // [8192,400]
{
    __shared__ float As[16][64];  // k-major
    __shared__ float Bs[16][64];

    const int tid = threadIdx.x;
    const int bm = blockIdx.x * 64;
    const int bn = blockIdx.y * 64;
    const int mt = tid % 16;  // m-tile index
    const int nt = tid / 16;  // n-tile index
    const int lr = tid / 4;         // 0..63: row within tile for loads
    const int lk = (tid % 4) * 4;   // 0,4,8,12: k within tile

    float acc[4][4] = {};

    for (int k0 = 0; k0 < 784; k0 += 16) {
        float4 a4 = *(const float4*)&h[(size_t)(bm + lr) * 784 + k0 + lk];
        float4 b4 = make_float4(0.f, 0.f, 0.f, 0.f);
        if (bn + lr < 400)
            b4 = *(const float4*)&w[(size_t)(bn + lr) * 784 + k0 + lk];
        __syncthreads();
        As[lk + 0][lr] = a4.x; As[lk + 1][lr] = a4.y;
        As[lk + 2][lr] = a4.z; As[lk + 3][lr] = a4.w;
        Bs[lk + 0][lr] = b4.x; Bs[lk + 1][lr] = b4.y;
        Bs[lk + 2][lr] = b4.z; Bs[lk + 3][lr] = b4.w;
        __syncthreads();
#pragma unroll
        for (int kk = 0; kk < 16; ++kk) {
            float4 av = *(const float4*)&As[kk][mt * 4];
            float4 bv = *(const float4*)&Bs[kk][nt * 4];
            float am[4] = {av.x, av.y, av.z, av.w};
            float bn_[4] = {bv.x, bv.y, bv.z, bv.w};
#pragma unroll
            for (int im = 0; im < 4; ++im)
#pragma unroll
                for (int in_ = 0; in_ < 4; ++in_)
                    acc[im][in_] += am[im] * bn_[in_];
        }
    }

#pragma unroll
    for (int im = 0; im < 4; ++im) {
        int row = bm + mt * 4 + im;
#pragma unroll
        for (int in_ = 0; in_ < 4; ++in_) {
            int col = bn + nt * 4 + in_;
            if (col < 400)
                h1[(size_t)row * 400 + col] = fmaxf(acc[im][in_] + bias[col], 0.f);
        }
    }
}

// ---------------------------------------------------------------------------
// K3: fc21 + fc22 fused  (mu, logvar) -> d_out tail
// block = 320 threads (5 waves) = 16 rows x 20 cols
// ---------------------------------------------------------------------------
__global__ __launch_bounds__(320) void fc2_kernel(
    const float* __restrict__ h1,   // [8192,400]
    const float* __restrict__ w21, const float* __restrict__ b21,
    const float* __restrict__ w22, const float* __restrict__ b22,
    float* __restrict__ out)
{
    __shared__ float hs[16 * 400];
    const int b0 = blockIdx.x * 16;
    const int tid = threadIdx.x;

    for (int i = tid; i < 16 * 400; i += 320)
        hs[i] = h1[(size_t)b0 * 400 + i];
    __syncthreads();

    const int row = tid / 20;
    const int j = tid % 20;

    float a1 = b21[j], a2 = b22[j];
    const float4* hrow = (const float4*)&hs[row * 400];
    const float4* wa = (const float4*)&w21[j * 400];
    const float4* wb = (const float4*)&w22[j * 400];
#pragma unroll 4
    for (int k = 0; k < 100; ++k) {
        float4 hv = hrow[k];
        float4 va = wa[k];
        float4 vb = wb[k];
        a1 += hv.x * va.x + hv.y * va.y + hv.z * va.z + hv.w * va.w;
        a2 += hv.x * vb.x + hv.y * vb.y + hv.z * vb.z + hv.w * vb.w;
    }
    size_t base = (size_t)BATCH * IMG;
    out[base + (size_t)(b0 + row) * 20 + j] = a1;
    out[base + (size_t)BATCH * 20 + (size_t)(b0 + row) * 20 + j] = a2;
}

// ---------------------------------------------------------------------------
// K4: decoder — fused fc3 + deconv0 + upsample(index math) + deconv1 +
// deconv2 + sigmoid. one block per image, 256 threads.
// ---------------------------------------------------------------------------
__global__ __launch_bounds__(256) void decoder_kernel(
    const int* __restrict__ cls,
    const float* __restrict__ fc3_w,  // [392,30]
    const float* __restrict__ fc3_b,  // [392]
    const float* __restrict__ dw0,    // [11,2,3,3]
    const float* __restrict__ dw1,    // [3,11,3,3]
    const float* __restrict__ dw2,    // [1,3,3,3]
    float* __restrict__ out)          // full d_out
{
    __shared__ float z[32];
    __shared__ float d0in[2][16][16];    // fc3 out [2,14,14] padded
    __shared__ float d0out[11][16][16];  // deconv0 out [11,14,14] padded
    __shared__ float d1[3][30][30];      // deconv1 out [3,28,28] padded

    const int b = blockIdx.x;
    const int tid = threadIdx.x;
    const int myc = cls[b];
    const float* mu = out + (size_t)BATCH * IMG + (size_t)b * 20;

    float* p0 = &d0in[0][0][0];
    for (int i = tid; i < 2 * 256; i += 256) p0[i] = 0.f;
    float* p1 = &d0out[0][0][0];
    for (int i = tid; i < 11 * 256; i += 256) p1[i] = 0.f;
    float* p2 = &d1[0][0][0];
    for (int i = tid; i < 3 * 900; i += 256) p2[i] = 0.f;
    if (tid < 20) z[tid] = mu[tid];
    else if (tid < 30) z[tid] = (tid - 20 == myc) ? 1.f : 0.f;
    __syncthreads();

    // fc3: [30] -> [392] + relu -> d0in as [2,14,14]
    for (int j = tid; j < 392; j += 256) {
        float acc = fc3_b[j];
        const float2* wrow = (const float2*)&fc3_w[j * 30];
#pragma unroll
        for (int k = 0; k < 15; ++k) {
            float2 wv = wrow[k];
            acc += z[2 * k] * wv.x + z[2 * k + 1] * wv.y;
        }
        int ch = j / 196, rem = j % 196;
        d0in[ch][rem / 14 + 1][rem % 14 + 1] = fmaxf(acc, 0.f);
    }
    __syncthreads();

    // deconv0: 2->11 ch on 14x14 + relu
    for (int idx = tid; idx < 11 * 196; idx += 256) {
        int o = idx / 196, rem = idx % 196;
        int r = rem / 14, c = rem % 14;
        float acc = 0.f;
#pragma unroll
        for (int i = 0; i < 2; ++i)
#pragma unroll
            for (int dr = 0; dr < 3; ++dr)
#pragma unroll
                for (int dc = 0; dc < 3; ++dc)
                    acc += d0in[i][r + dr][c + dc] *
                           dw0[((o * 2 + i) * 3 + dr) * 3 + dc];
        d0out[o][r + 1][c + 1] = fmaxf(acc, 0.f);
    }
    __syncthreads();

    // deconv1 on upsampled 28x28 (nearest x2 via index math) + relu
    for (int pix = tid; pix < 784; pix += 256) {
        int r = pix / 28, c = pix % 28;
        float a0 = 0.f, a1 = 0.f, a2 = 0.f;
#pragma unroll
        for (int i = 0; i < 11; ++i)
#pragma unroll
            for (int dr = 0; dr < 3; ++dr)
#pragma unroll
                for (int dc = 0; dc < 3; ++dc) {
                    int R = r + dr - 1;  // -1..28
                    int C = c + dc - 1;
                    // up[R][C] = d0out_unpadded[R/2][C/2]; arithmetic >>1
                    // maps -1 -> row 0 (zero border), 28 -> row 15 (zero border)
                    float v = d0out[i][(R >> 1) + 1][(C >> 1) + 1];
                    int wi = (i * 3 + dr) * 3 + dc;
                    a0 += v * dw1[wi];
                    a1 += v * dw1[99 + wi];
                    a2 += v * dw1[198 + wi];
                }
        d1[0][r + 1][c + 1] = fmaxf(a0, 0.f);
        d1[1][r + 1][c + 1] = fmaxf(a1, 0.f);
        d1[2][r + 1][c + 1] = fmaxf(a2, 0.f);
    }
    __syncthreads();

    // deconv2 (3->1) + sigmoid -> recon
    for (int pix = tid; pix < 784; pix += 256) {
        int r = pix / 28, c = pix % 28;
        float a = 0.f;
#pragma unroll
        for (int i = 0; i < 3; ++i)
#pragma unroll
            for (int dr = 0; dr < 3; ++dr)
#pragma unroll
                for (int dc = 0; dc < 3; ++dc)
                    a += d1[i][r + dr][c + dc] * dw2[(i * 3 + dr) * 3 + dc];
        out[(size_t)b * IMG + pix] = 1.f / (1.f + expf(-a));
    }
}

// ---------------------------------------------------------------------------
extern "C" void kernel_launch(void* const* d_in, const int* in_sizes, int n_in,
                              void* d_out, int out_size, void* d_ws, size_t ws_size,
                              hipStream_t stream) {
    const float* x     = (const float*)d_in[0];
    const int*   cls   = (const int*)d_in[1];
    const float* w0    = (const float*)d_in[2];
    const float* w1    = (const float*)d_in[3];
    const float* fc1_w = (const float*)d_in[4];
    const float* fc1_b = (const float*)d_in[5];
    const float* w21   = (const float*)d_in[6];
    const float* b21   = (const float*)d_in[7];
    const float* w22   = (const float*)d_in[8];
    const float* b22   = (const float*)d_in[9];
    const float* fc3_w = (const float*)d_in[10];
    const float* fc3_b = (const float*)d_in[11];
    const float* dw0   = (const float*)d_in[12];
    const float* dw1   = (const float*)d_in[13];
    const float* dw2   = (const float*)d_in[14];

    float* out = (float*)d_out;
    float* ws  = (float*)d_ws;
    float* h   = ws;                          // [8192,784]
    float* h1  = ws + (size_t)BATCH * IMG;    // [8192,400]

    encoder_kernel<<<BATCH, 256, 0, stream>>>(x, cls, w0, w1, h);
    fc1_gemm<<<dim3(BATCH / 64, 7), 256, 0, stream>>>(h, fc1_w, fc1_b, h1);
    fc2_kernel<<<BATCH / 16, 320, 0, stream>>>(h1, w21, b21, w22, b22, out);
    decoder_kernel<<<BATCH, 256, 0, stream>>>(cls, fc3_w, fc3_b, dw0, dw1, dw2, out);
}

// Round 2
// 345.456 us; speedup vs baseline: 1.8757x; 1.8757x over previous
//
#include <hip/hip_runtime.h>
#include <hip/hip_bf16.h>
#include <math.h>

#define BATCH 8192
#define IMG 784  // 28*28

// ---------------------------------------------------------------------------
// K0: precompute per-class conv0 one-hot tables T[10][3][28][28] and
// parity-folded deconv1 weights Weff[4][3][11][4]. Runs every launch (cheap).
//
// e_input structure: flat f = ch*784 + s (s = rr*28+cc); source element
// k = f mod 11 (784 = 71*11+3 -> k = (3*ch + s) mod 11). k==0 -> x pixel,
// k==t+1 -> 1.0 for class t, else 0. For fixed s, each residue k occurs in
// exactly one channel: i = 4*(k - s) mod 11  (4 = inv(3) mod 11).
// ---------------------------------------------------------------------------
__global__ __launch_bounds__(256) void precompute_kernel(
    const float* __restrict__ w0,   // [3,11,3,3]
    const float* __restrict__ dw1,  // [3,11,3,3]
    float* __restrict__ T,          // [10,3,784]
    float* __restrict__ Weff)       // [4,3,11,4]
{
    const int blk = blockIdx.x, tid = threadIdx.x;
    if (blk < 10) {
        const int t = blk;
        for (int idx = tid; idx < 3 * 784; idx += 256) {
            int o = idx / 784, pix = idx % 784;
            int r = pix / 28, c = pix % 28;
            float acc = 0.f;
#pragma unroll
            for (int dr = 0; dr < 3; ++dr)
#pragma unroll
                for (int dc = 0; dc < 3; ++dc) {
                    int rr = r + dr - 1, cc = c + dc - 1;
                    if (rr < 0 || rr > 27 || cc < 0 || cc > 27) continue;
                    int s = rr * 28 + cc;
                    int i = ((4 * (t + 1 - s)) % 11 + 11) % 11;
                    acc += w0[(o * 11 + i) * 9 + dr * 3 + dc];
                }
            T[(t * 3 + o) * 784 + pix] = acc;
        }
    } else {
        // Weff[par][o][i][u*2+v]: fold 3x3 taps over nearest-2x upsample into
        // a 2x2 kernel per output-pixel parity.
        for (int idx = tid; idx < 528; idx += 256) {
            int par = idx / 132, rem = idx % 132;
            int o = rem / 44, rem2 = rem % 44;
            int i = rem2 / 4, uv = rem2 % 4;
            int u = uv >> 1, v = uv & 1;
            int pr = par >> 1, pc = par & 1;
            float acc = 0.f;
            for (int dr = 0; dr < 3; ++dr) {
                bool rin = (pr == 0) ? (u == 0 ? dr == 0 : dr >= 1)
                                     : (u == 0 ? dr <= 1 : dr == 2);
                if (!rin) continue;
                for (int dc = 0; dc < 3; ++dc) {
                    bool cin = (pc == 0) ? (v == 0 ? dc == 0 : dc >= 1)
                                         : (v == 0 ? dc <= 1 : dc == 2);
                    if (cin) acc += dw1[(o * 11 + i) * 9 + dr * 3 + dc];
                }
            }
            Weff[idx] = acc;
        }
    }
}

// ---------------------------------------------------------------------------
// K1: encoder — sparse-x conv0 (9 taps) + class table T + conv1
// one block per image, 256 threads
// ---------------------------------------------------------------------------
__global__ __launch_bounds__(256) void encoder_kernel(
    const float* __restrict__ x, const int* __restrict__ cls,
    const float* __restrict__ w0,   // [3,11,3,3]
    const float* __restrict__ w1,   // [1,3,3,3]
    const float* __restrict__ T,    // [10,3,784]
    float* __restrict__ h_out)      // [B,784]
{
    __shared__ float xs[30][30];        // scattered x image, zero-padded
    __shared__ float h0[3][30][30];     // conv0 out, zero-padded
    __shared__ float4 wt[99];           // [tap][ch] -> (w_o0, w_o1, w_o2, 0)

    const int b = blockIdx.x, tid = threadIdx.x;
    const int myc = cls[b];

    for (int i = tid; i < 900; i += 256) (&xs[0][0])[i] = 0.f;
    for (int i = tid; i < 2700; i += 256) (&h0[0][0][0])[i] = 0.f;
    for (int i = tid; i < 99; i += 256) {
        int tap = i / 11, ch = i % 11;
        wt[i] = make_float4(w0[ch * 9 + tap], w0[(11 + ch) * 9 + tap],
                            w0[(22 + ch) * 9 + tap], 0.f);
    }
    __syncthreads();

    // xs[rr][cc] = x value living at spatial position s (unique channel)
    for (int s = tid; s < 784; s += 256) {
        int ch = (7 * s) % 11;            // channel containing x at s
        int p = (ch * 784 + s) / 11;      // exact
        xs[s / 28 + 1][s % 28 + 1] = x[(size_t)b * IMG + p];
    }
    __syncthreads();

    const float* Tc = T + myc * 2352;
    for (int pix = tid; pix < 784; pix += 256) {
        int r = pix / 28, c = pix % 28;
        float a0 = Tc[pix], a1 = Tc[784 + pix], a2 = Tc[1568 + pix];
        int chbase = (9 * r + 7 * c + 6) % 11;  // ch at tap (dr,dc)=(0,0)
#pragma unroll
        for (int dr = 0; dr < 3; ++dr)
#pragma unroll
            for (int dc = 0; dc < 3; ++dc) {
                const int kk = (9 * dr + 7 * dc) % 11;  // compile-time
                int ch = chbase + kk;
                if (ch >= 11) ch -= 11;
                float v = xs[r + dr][c + dc];
                float4 w = wt[(dr * 3 + dc) * 11 + ch];
                a0 += v * w.x; a1 += v * w.y; a2 += v * w.z;
            }
        h0[0][r + 1][c + 1] = fmaxf(a0, 0.f);
        h0[1][r + 1][c + 1] = fmaxf(a1, 0.f);
        h0[2][r + 1][c + 1] = fmaxf(a2, 0.f);
    }
    __syncthreads();

    for (int pix = tid; pix < 784; pix += 256) {
        int r = pix / 28, c = pix % 28;
        float a = 0.f;
#pragma unroll
        for (int i3 = 0; i3 < 3; ++i3)
#pragma unroll
            for (int dr = 0; dr < 3; ++dr)
#pragma unroll
                for (int dc = 0; dc < 3; ++dc)
                    a += h0[i3][r + dr][c + dc] * w1[(i3 * 3 + dr) * 3 + dc];
        h_out[(size_t)b * IMG + pix] = fmaxf(a, 0.f);
    }
}

// ---------------------------------------------------------------------------
// K2: fc1 GEMM  h1[8192,400] = relu(h[8192,784] @ w^T + b)
// ---------------------------------------------------------------------------
__global__ __launch_bounds__(256) void fc1_gemm(
    const float* __restrict__ h, const float* __restrict__ w,
    const float* __restrict__ bias, float* __restrict__ h1)
{
    __shared__ float As[16][64];
    __shared__ float Bs[16][64];

    const int tid = threadIdx.x;
    const int bm = blockIdx.x * 64;
    const int bn = blockIdx.y * 64;
    const int mt = tid % 16;
    const int nt = tid / 16;
    const int lr = tid / 4;
    const int lk = (tid % 4) * 4;

    float acc[4][4] = {};

    for (int k0 = 0; k0 < 784; k0 += 16) {
        float4 a4 = *(const float4*)&h[(size_t)(bm + lr) * 784 + k0 + lk];
        float4 b4 = make_float4(0.f, 0.f, 0.f, 0.f);
        if (bn + lr < 400)
            b4 = *(const float4*)&w[(size_t)(bn + lr) * 784 + k0 + lk];
        __syncthreads();
        As[lk + 0][lr] = a4.x; As[lk + 1][lr] = a4.y;
        As[lk + 2][lr] = a4.z; As[lk + 3][lr] = a4.w;
        Bs[lk + 0][lr] = b4.x; Bs[lk + 1][lr] = b4.y;
        Bs[lk + 2][lr] = b4.z; Bs[lk + 3][lr] = b4.w;
        __syncthreads();
#pragma unroll
        for (int kk = 0; kk < 16; ++kk) {
            float4 av = *(const float4*)&As[kk][mt * 4];
            float4 bv = *(const float4*)&Bs[kk][nt * 4];
            float am[4] = {av.x, av.y, av.z, av.w};
            float bn_[4] = {bv.x, bv.y, bv.z, bv.w};
#pragma unroll
            for (int im = 0; im < 4; ++im)
#pragma unroll
                for (int in_ = 0; in_ < 4; ++in_)
                    acc[im][in_] += am[im] * bn_[in_];
        }
    }

#pragma unroll
    for (int im = 0; im < 4; ++im) {
        int row = bm + mt * 4 + im;
#pragma unroll
        for (int in_ = 0; in_ < 4; ++in_) {
            int col = bn + nt * 4 + in_;
            if (col < 400)
                h1[(size_t)row * 400 + col] = fmaxf(acc[im][in_] + bias[col], 0.f);
        }
    }
}

// ---------------------------------------------------------------------------
// K3: fc21 + fc22 fused
// ---------------------------------------------------------------------------
__global__ __launch_bounds__(320) void fc2_kernel(
    const float* __restrict__ h1,
    const float* __restrict__ w21, const float* __restrict__ b21,
    const float* __restrict__ w22, const float* __restrict__ b22,
    float* __restrict__ out)
{
    __shared__ float hs[16 * 400];
    const int b0 = blockIdx.x * 16;
    const int tid = threadIdx.x;

    for (int i = tid; i < 16 * 400; i += 320)
        hs[i] = h1[(size_t)b0 * 400 + i];
    __syncthreads();

    const int row = tid / 20;
    const int j = tid % 20;

    float a1 = b21[j], a2 = b22[j];
    const float4* hrow = (const float4*)&hs[row * 400];
    const float4* wa = (const float4*)&w21[j * 400];
    const float4* wb = (const float4*)&w22[j * 400];
#pragma unroll 4
    for (int k = 0; k < 100; ++k) {
        float4 hv = hrow[k];
        float4 va = wa[k];
        float4 vb = wb[k];
        a1 += hv.x * va.x + hv.y * va.y + hv.z * va.z + hv.w * va.w;
        a2 += hv.x * vb.x + hv.y * vb.y + hv.z * vb.z + hv.w * vb.w;
    }
    size_t base = (size_t)BATCH * IMG;
    out[base + (size_t)(b0 + row) * 20 + j] = a1;
    out[base + (size_t)BATCH * 20 + (size_t)(b0 + row) * 20 + j] = a2;
}

// ---------------------------------------------------------------------------
// K4: decoder — fc3 + deconv0 + parity-folded deconv1 + deconv2 + sigmoid
// ---------------------------------------------------------------------------
__global__ __launch_bounds__(256) void decoder_kernel(
    const int* __restrict__ cls,
    const float* __restrict__ fc3_w,  // [392,30]
    const float* __restrict__ fc3_b,  // [392]
    const float* __restrict__ dw0,    // [11,2,3,3]
    const float* __restrict__ dw2,    // [1,3,3,3]
    const float* __restrict__ Weff,   // [4,3,11,4]
    float* __restrict__ out)
{
    __shared__ float z[32];
    __shared__ float d0in[2][16][16];
    __shared__ float d0out[11][16][16];
    __shared__ float d1[3][30][30];
    __shared__ float4 we[132];          // Weff copy: [par][o][i]

    const int b = blockIdx.x;
    const int tid = threadIdx.x;
    const int myc = cls[b];
    const float* mu = out + (size_t)BATCH * IMG + (size_t)b * 20;

    float* p0 = &d0in[0][0][0];
    for (int i = tid; i < 2 * 256; i += 256) p0[i] = 0.f;
    float* p1 = &d0out[0][0][0];
    for (int i = tid; i < 11 * 256; i += 256) p1[i] = 0.f;
    float* p2 = &d1[0][0][0];
    for (int i = tid; i < 3 * 900; i += 256) p2[i] = 0.f;
    for (int i = tid; i < 132; i += 256) we[i] = ((const float4*)Weff)[i];
    if (tid < 20) z[tid] = mu[tid];
    else if (tid < 30) z[tid] = (tid - 20 == myc) ? 1.f : 0.f;
    __syncthreads();

    // fc3: [30] -> [392] + relu
    for (int j = tid; j < 392; j += 256) {
        float acc = fc3_b[j];
        const float2* wrow = (const float2*)&fc3_w[j * 30];
#pragma unroll
        for (int k = 0; k < 15; ++k) {
            float2 wv = wrow[k];
            acc += z[2 * k] * wv.x + z[2 * k + 1] * wv.y;
        }
        int ch = j / 196, rem = j % 196;
        d0in[ch][rem / 14 + 1][rem % 14 + 1] = fmaxf(acc, 0.f);
    }
    __syncthreads();

    // deconv0: 2->11 ch on 14x14 + relu (uniform weights -> s_loads)
    for (int idx = tid; idx < 11 * 196; idx += 256) {
        int o = idx / 196, rem = idx % 196;
        int r = rem / 14, c = rem % 14;
        float acc = 0.f;
#pragma unroll
        for (int i = 0; i < 2; ++i)
#pragma unroll
            for (int dr = 0; dr < 3; ++dr)
#pragma unroll
                for (int dc = 0; dc < 3; ++dc)
                    acc += d0in[i][r + dr][c + dc] *
                           dw0[((o * 2 + i) * 3 + dr) * 3 + dc];
        d0out[o][r + 1][c + 1] = fmaxf(acc, 0.f);
    }
    __syncthreads();

    // deconv1 via parity-folded 2x2 kernels: out pixel (2qr+pr, 2qc+pc)
    // reads d0out rows {base, base+1}, base = qr+pr (padded coords).
#pragma unroll 1
    for (int par = 0; par < 4; ++par) {
        int pr = par >> 1, pc = par & 1;
        if (tid < 196) {
            int qr = tid / 14, qc = tid % 14;
            int rb = qr + pr, cb = qc + pc;
            float a0 = 0.f, a1 = 0.f, a2 = 0.f;
#pragma unroll
            for (int i = 0; i < 11; ++i) {
                float v00 = d0out[i][rb][cb],     v01 = d0out[i][rb][cb + 1];
                float v10 = d0out[i][rb + 1][cb], v11 = d0out[i][rb + 1][cb + 1];
                float4 wv0 = we[par * 33 + i];
                float4 wv1 = we[par * 33 + 11 + i];
                float4 wv2 = we[par * 33 + 22 + i];
                a0 += v00 * wv0.x + v01 * wv0.y + v10 * wv0.z + v11 * wv0.w;
                a1 += v00 * wv1.x + v01 * wv1.y + v10 * wv1.z + v11 * wv1.w;
                a2 += v00 * wv2.x + v01 * wv2.y + v10 * wv2.z + v11 * wv2.w;
            }
            int r = 2 * qr + pr, c = 2 * qc + pc;
            d1[0][r + 1][c + 1] = fmaxf(a0, 0.f);
            d1[1][r + 1][c + 1] = fmaxf(a1, 0.f);
            d1[2][r + 1][c + 1] = fmaxf(a2, 0.f);
        }
    }
    __syncthreads();

    // deconv2 (3->1) + sigmoid
    for (int pix = tid; pix < 784; pix += 256) {
        int r = pix / 28, c = pix % 28;
        float a = 0.f;
#pragma unroll
        for (int i = 0; i < 3; ++i)
#pragma unroll
            for (int dr = 0; dr < 3; ++dr)
#pragma unroll
                for (int dc = 0; dc < 3; ++dc)
                    a += d1[i][r + dr][c + dc] * dw2[(i * 3 + dr) * 3 + dc];
        out[(size_t)b * IMG + pix] = 1.f / (1.f + expf(-a));
    }
}

// ---------------------------------------------------------------------------
extern "C" void kernel_launch(void* const* d_in, const int* in_sizes, int n_in,
                              void* d_out, int out_size, void* d_ws, size_t ws_size,
                              hipStream_t stream) {
    const float* x     = (const float*)d_in[0];
    const int*   cls   = (const int*)d_in[1];
    const float* w0    = (const float*)d_in[2];
    const float* w1    = (const float*)d_in[3];
    const float* fc1_w = (const float*)d_in[4];
    const float* fc1_b = (const float*)d_in[5];
    const float* w21   = (const float*)d_in[6];
    const float* b21   = (const float*)d_in[7];
    const float* w22   = (const float*)d_in[8];
    const float* b22   = (const float*)d_in[9];
    const float* fc3_w = (const float*)d_in[10];
    const float* fc3_b = (const float*)d_in[11];
    const float* dw0   = (const float*)d_in[12];
    const float* dw1   = (const float*)d_in[13];
    const float* dw2   = (const float*)d_in[14];

    float* out = (float*)d_out;
    float* ws  = (float*)d_ws;
    float* h    = ws;                                     // [8192,784]
    float* h1   = ws + (size_t)BATCH * IMG;               // [8192,400]
    float* T    = h1 + (size_t)BATCH * 400;               // [10,3,784]
    float* Weff = T + 10 * 3 * 784;                       // [4,3,11,4]

    precompute_kernel<<<11, 256, 0, stream>>>(w0, dw1, T, Weff);
    encoder_kernel<<<BATCH, 256, 0, stream>>>(x, cls, w0, w1, T, h);
    fc1_gemm<<<dim3(BATCH / 64, 7), 256, 0, stream>>>(h, fc1_w, fc1_b, h1);
    fc2_kernel<<<BATCH / 16, 320, 0, stream>>>(h1, w21, b21, w22, b22, out);
    decoder_kernel<<<BATCH, 256, 0, stream>>>(cls, fc3_w, fc3_b, dw0, dw2, Weff, out);
}